// Round 13
// baseline (128.058 us; speedup 1.0000x reference)
//
#include <hip/hip_runtime.h>
#include <hip/hip_fp16.h>

// Ultimus: out = x + softmax((x@Kw+Kb)@(x@Qw+Qb)^T / sqrt(8)) @ (x@Vw+Vb) @ Zw + Zb
// N=8192, D_IN=48, D_ATTN=8, fp32 in/out.
//
// R13: amortized LDS broadcast — 4 rows per lane.
// R12 post-mortem: hot loop was DS-pipe-bound: 4 uniform ds_read_b128/pair
// PER WAVE => 32 waves/CU x 64 pairs x 4 x 12cyc = 98k cyc/CU = 41 us,
// matching attn ~37 us. DS cost scales 1/R with R rows/lane (VALU invariant).
// R=4: DS 10.2 us, VALU ~11.7 us, overlapped pipes => attn ~13 us.
//  - single-wave (64-thr) blocks, no merge (disjoint rows), no barrier cost
//  - guaranteed packed math: inline-asm v_pk_fma_f16 (17/pair/row)
//  - bound-softmax (Cauchy-Schwarz) => fixed exponent shift, partials add
//  - f16 c-major partials (128 slices, 18.9 MB, L3-resident), finish sums
//
// ws layout (floats):
//   [0, 32768)      Xksf16[8192] 8 f16/row (k * log2e/sqrt(8)), uint4/row
//   [32768, 98304)  QV per pair p: 16 dwords = q2pair[8] | v2pair[8]
//                   (dword c of pair p = half2(val[2p][c], val[2p+1][c]))
//   [98304, 98560)  bmax[256] per-proj-block max ||q||^2 (plain store)
//   [98560, ...)    partH[nch][9][8192] f16 partials, c-major

#define QV_OFF   32768
#define BMAX_OFF 98304
#define PART_OFF 98560

typedef _Float16 hv2 __attribute__((ext_vector_type(2)));
union HVU { unsigned u; hv2 v; };

static __device__ __forceinline__ unsigned pku(float a, float b) {
    auto t = __builtin_amdgcn_cvt_pkrtz(a, b);
    union { decltype(t) x; unsigned u; } c; c.x = t; return c.u;
}
static __device__ __forceinline__ hv2 asV(unsigned u) { HVU t; t.u = u; return t.v; }
static __device__ __forceinline__ unsigned dupL(unsigned u) {
    const unsigned lo = u & 0xFFFFu; return lo | (lo << 16);
}
static __device__ __forceinline__ unsigned dupH(unsigned u) {
    const unsigned hi = u >> 16; return hi | (hi << 16);
}
// d += a*b on packed f16 pairs — guaranteed v_pk_fma_f16
static __device__ __forceinline__ void pkfma(unsigned& d, unsigned a, unsigned b) {
    asm("v_pk_fma_f16 %0, %1, %2, %0" : "+v"(d) : "v"(a), "v"(b));
}

__global__ __launch_bounds__(256) void proj_kernel(
    const float* __restrict__ x,
    const float* __restrict__ Kw, const float* __restrict__ Kb,
    const float* __restrict__ Qw, const float* __restrict__ Qb,
    const float* __restrict__ Vw, const float* __restrict__ Vb,
    unsigned* __restrict__ Xksf16, unsigned* __restrict__ QV,
    float* __restrict__ bmax)
{
    __shared__ float xs[32 * 49];     // +1 pad
    __shared__ float wAll[3 * 388];   // stride 388 (mod 32 = 4) spreads 3 mats
    __shared__ float bs[24];
    __shared__ float outv[32][25];    // 24 cols + pad
    const int tid = threadIdx.x;
    const int r0 = blockIdx.x * 32;

    for (int i = tid; i < 1536; i += 256) {
        int r = i / 48, c = i - r * 48;
        xs[r * 49 + c] = x[r0 * 48 + i];
    }
    for (int i = tid; i < 384; i += 256) {
        wAll[i]       = Kw[i];
        wAll[388 + i] = Qw[i];
        wAll[776 + i] = Vw[i];
    }
    if (tid < 8)       bs[tid] = Kb[tid];
    else if (tid < 16) bs[tid] = Qb[tid - 8];
    else if (tid < 24) bs[tid] = Vb[tid - 16];
    __syncthreads();

    const int rl = tid >> 3;
    const int g  = tid & 7;
    const int c0 = 3 * g;
    const float* xr = &xs[rl * 49];
    const float* w0 = &wAll[((c0 + 0) >> 3) * 388 + ((c0 + 0) & 7)];
    const float* w1 = &wAll[((c0 + 1) >> 3) * 388 + ((c0 + 1) & 7)];
    const float* w2 = &wAll[((c0 + 2) >> 3) * 388 + ((c0 + 2) & 7)];
    float a0 = bs[c0], a1 = bs[c0 + 1], a2 = bs[c0 + 2];
    #pragma unroll
    for (int k = 0; k < 48; k++) {
        const float xv = xr[k];
        a0 = fmaf(xv, w0[k * 8], a0);
        a1 = fmaf(xv, w1[k * 8], a1);
        a2 = fmaf(xv, w2[k * 8], a2);
    }
    outv[rl][c0] = a0; outv[rl][c0 + 1] = a1; outv[rl][c0 + 2] = a2;
    __syncthreads();

    // QV pair-interleaved: pair p (16/block), col c (8), m: 0=q, 1=v
    {
        const int p = tid >> 4;
        const int c = (tid >> 1) & 7;
        const int m = tid & 1;
        const int col = (m ? 16 : 8) + c;
        QV[(blockIdx.x * 16 + p) * 16 + m * 8 + c] =
            pku(outv[2 * p][col], outv[2 * p + 1][col]);
    }
    const float kscale = 0.51008732149f;  // (1/sqrt(8)) * log2(e)
    if (tid < 32) {                       // K rows, f16 packed, pre-scaled
        uint4 o;
        o.x = pku(outv[tid][0] * kscale, outv[tid][1] * kscale);
        o.y = pku(outv[tid][2] * kscale, outv[tid][3] * kscale);
        o.z = pku(outv[tid][4] * kscale, outv[tid][5] * kscale);
        o.w = pku(outv[tid][6] * kscale, outv[tid][7] * kscale);
        ((uint4*)Xksf16)[r0 + tid] = o;
    }
    if (tid >= 192 && tid < 224) {        // block-max ||q||^2 (fp32)
        const int r = tid - 192;
        float n2 = 0.f;
        #pragma unroll
        for (int c = 0; c < 8; c++) n2 = fmaf(outv[r][8 + c], outv[r][8 + c], n2);
        #pragma unroll
        for (int off = 16; off > 0; off >>= 1)
            n2 = fmaxf(n2, __shfl_xor(n2, off, 64));
        if (r == 0) bmax[blockIdx.x] = n2;
    }
}

// grid = 32 row-groups (256 rows: 64 lanes x 4 rows/lane) x nch chunks.
// Single-wave blocks; tile staged 32 pairs at a time; uniform ds_read_b128
// broadcast amortized over 4 rows/lane.
__global__ __launch_bounds__(64) void attn_kernel(
    const unsigned* __restrict__ Xksf16, const unsigned* __restrict__ QV,
    const float* __restrict__ bmax,
    __half* __restrict__ partH, int P)
{
    __shared__ uint4 tile4[128];       // 32 pairs x 4 uint4 = 2 KB
    const int lane  = threadIdx.x;
    const int g     = blockIdx.x & 31;
    const int chunk = blockIdx.x >> 5;

    // qmax2 = max over 256 per-proj-block maxima
    float m = fmaxf(fmaxf(bmax[lane], bmax[64 + lane]),
                    fmaxf(bmax[128 + lane], bmax[192 + lane]));
    #pragma unroll
    for (int off = 32; off > 0; off >>= 1)
        m = fmaxf(m, __shfl_xor(m, off, 64));
    const float qmax2 = m;

    unsigned kd[4][8], sinit2[4], l2[4], acc[4][8];
    #pragma unroll
    for (int k = 0; k < 4; k++) {
        const int row = g * 256 + k * 64 + lane;          // coalesced per k
        const uint4 kv = ((const uint4*)Xksf16)[row];
        kd[k][0] = dupL(kv.x); kd[k][1] = dupH(kv.x);
        kd[k][2] = dupL(kv.y); kd[k][3] = dupH(kv.y);
        kd[k][4] = dupL(kv.z); kd[k][5] = dupH(kv.z);
        kd[k][6] = dupL(kv.w); kd[k][7] = dupH(kv.w);
        float kn2 = 0.f;
        #pragma unroll
        for (int c = 0; c < 8; c++) {
            const float kf = (float)asV(kd[k][c]).x;
            kn2 = fmaf(kf, kf, kn2);
        }
        const float sinit = -sqrtf(kn2 * qmax2);  // s <= -sinit: p in (0,~1]
        sinit2[k] = pku(sinit, sinit);
        l2[k] = 0u;
        #pragma unroll
        for (int c = 0; c < 8; c++) acc[k][c] = 0u;
    }
    const unsigned one2 = 0x3C003C00u;

    for (int t0 = 0; t0 < P; t0 += 32) {
        __syncthreads();               // cheap: single wave
        tile4[lane]      = ((const uint4*)QV)[((size_t)chunk * P + t0) * 4 + lane];
        tile4[lane + 64] = ((const uint4*)QV)[((size_t)chunk * P + t0) * 4 + lane + 64];
        __syncthreads();

        #pragma unroll 2
        for (int p = 0; p < 32; p++) {
            // wave-uniform ds_read_b128 x4: broadcast, amortized over 4 rows
            const uint4 qp0 = tile4[p * 4 + 0];   // q2pair c0..3
            const uint4 qp1 = tile4[p * 4 + 1];   // q2pair c4..7
            const uint4 vp0 = tile4[p * 4 + 2];   // v2pair c0..3
            const uint4 vp1 = tile4[p * 4 + 3];   // v2pair c4..7
            #pragma unroll
            for (int k = 0; k < 4; k++) {
                unsigned s2 = sinit2[k];
                pkfma(s2, kd[k][0], qp0.x);
                pkfma(s2, kd[k][1], qp0.y);
                pkfma(s2, kd[k][2], qp0.z);
                pkfma(s2, kd[k][3], qp0.w);
                pkfma(s2, kd[k][4], qp1.x);
                pkfma(s2, kd[k][5], qp1.y);
                pkfma(s2, kd[k][6], qp1.z);
                pkfma(s2, kd[k][7], qp1.w);
                const hv2 sv = asV(s2);
                const float pa = __builtin_amdgcn_exp2f((float)sv.x);
                const float pb = __builtin_amdgcn_exp2f((float)sv.y);
                const unsigned ph = pku(pa, pb);
                pkfma(l2[k], ph, one2);
                pkfma(acc[k][0], ph, vp0.x);
                pkfma(acc[k][1], ph, vp0.y);
                pkfma(acc[k][2], ph, vp0.z);
                pkfma(acc[k][3], ph, vp0.w);
                pkfma(acc[k][4], ph, vp1.x);
                pkfma(acc[k][5], ph, vp1.y);
                pkfma(acc[k][6], ph, vp1.z);
                pkfma(acc[k][7], ph, vp1.w);
            }
        }
    }

    // c-major f16 partial store: lanes = consecutive rows (coalesced)
    #pragma unroll
    for (int k = 0; k < 4; k++) {
        const int row = g * 256 + k * 64 + lane;
        #pragma unroll
        for (int c = 0; c < 8; c++) {
            const hv2 a = asV(acc[k][c]);
            partH[((size_t)(chunk * 9 + c) << 13) + row] =
                __float2half_rn((float)a.x + (float)a.y);
        }
        const hv2 lv = asV(l2[k]);
        partH[((size_t)(chunk * 9 + 8) << 13) + row] =
            __float2half_rn((float)lv.x + (float)lv.y);
    }
}

// grid = 128 blocks x 64 rows; thread (r = tid&63, slice-group s = tid>>6)
__global__ __launch_bounds__(256) void finish_kernel(
    const float* __restrict__ x,
    const float* __restrict__ Zw, const float* __restrict__ Zb,
    const __half* __restrict__ partH, float* __restrict__ out, int nch)
{
    __shared__ float red[4][64][10];
    __shared__ float Zs[64][9];
    __shared__ float zw_s[384];
    __shared__ float zb_s[48];
    const int tid = threadIdx.x;
    const int r0 = blockIdx.x * 64;

    for (int i = tid; i < 384; i += 256) zw_s[i] = Zw[i];
    if (tid < 48) zb_s[tid] = Zb[tid];

    const int r = tid & 63, s = tid >> 6;
    const int row = r0 + r;
    const int cps = nch >> 2;
    float a[9];
    #pragma unroll
    for (int c = 0; c < 9; c++) a[c] = 0.f;
    for (int i = 0; i < cps; i++) {
        const int ch = s * cps + i;
        const __half* p = partH + ((size_t)(ch * 9) << 13) + row;
        #pragma unroll
        for (int c = 0; c < 9; c++) a[c] += __half2float(p[(size_t)c << 13]);
    }
    #pragma unroll
    for (int c = 0; c < 9; c++) red[s][r][c] = a[c];
    __syncthreads();
    if (tid < 64) {
        float b[9];
        #pragma unroll
        for (int c = 0; c < 9; c++)
            b[c] = red[0][tid][c] + red[1][tid][c] + red[2][tid][c] + red[3][tid][c];
        const float inv = 1.0f / b[8];
        #pragma unroll
        for (int c = 0; c < 8; c++) Zs[tid][c] = b[c] * inv;
    }
    __syncthreads();

    for (int e = tid; e < 64 * 48; e += 256) {
        const int rr = e / 48, c = e - rr * 48;
        float o = x[r0 * 48 + e] + zb_s[c];
        #pragma unroll
        for (int k = 0; k < 8; k++) o = fmaf(Zs[rr][k], zw_s[k * 48 + c], o);
        out[r0 * 48 + e] = o;
    }
}

extern "C" void kernel_launch(void* const* d_in, const int* in_sizes, int n_in,
                              void* d_out, int out_size, void* d_ws, size_t ws_size,
                              hipStream_t stream) {
    const float* x  = (const float*)d_in[0];
    const float* Kw = (const float*)d_in[1];
    const float* Kb = (const float*)d_in[2];
    const float* Qw = (const float*)d_in[3];
    const float* Qb = (const float*)d_in[4];
    const float* Vw = (const float*)d_in[5];
    const float* Vb = (const float*)d_in[6];
    const float* Zw = (const float*)d_in[7];
    const float* Zb = (const float*)d_in[8];
    float* out = (float*)d_out;

    float* ws = (float*)d_ws;
    unsigned* Xksf16 = (unsigned*)ws;
    unsigned* QV     = (unsigned*)(ws + QV_OFF);
    float* bmax      = ws + BMAX_OFF;
    __half* partH    = (__half*)(ws + PART_OFF);

    // largest chunk count whose f16 partials fit the workspace
    int nch = 128;
    while (nch > 4 &&
           (size_t)PART_OFF * 4 + (size_t)nch * 9 * 8192 * 2 > ws_size) nch >>= 1;
    const int P = 4096 / nch;   // j-pairs per chunk (32 when nch=128)

    proj_kernel<<<256, 256, 0, stream>>>(x, Kw, Kb, Qw, Qb, Vw, Vb,
                                         Xksf16, QV, bmax);
    attn_kernel<<<32 * nch, 64, 0, stream>>>(Xksf16, QV, bmax, partH, P);
    finish_kernel<<<128, 256, 0, stream>>>(x, Zw, Zb, partH, out, nch);
}